// Round 15
// baseline (92.282 us; speedup 1.0000x reference)
//
#include <hip/hip_runtime.h>

#define TRAIN_ROIS 256
#define POS_QUOTA 25          // int(0.1 * 256)
#define POS_THR 0.5f
#define NEG_THR 0.02f
#define EPS 1e-8f
#define G_MAX 32
#define B_MAX 16
#define SEG 1024              // placement segment
#define SEG_A 256             // phaseA quarter-segment (= its block size)
#define GT_STRIDE 194         // even (float2-aligned); i*194%32=2i -> disjoint bank pairs
#define VOL_STRIDE 33         // (i*33+g)%32=(i+g)%32 -> bank-spread volumes

// Phase A (unchanged, proven): one thread per proposal, 256 blocks of 256.
// Pos/neg tie bitmasks + per-quarter counts stored transposed
// (gcntSegT[slot][quarter], slot=it*32+g); full-mask counted separately.
__launch_bounds__(SEG_A)
__global__ void phaseA(const float* __restrict__ props, const int* __restrict__ bidx,
                       const float* __restrict__ gtb,
                       unsigned int* __restrict__ posBits, unsigned int* __restrict__ negBits,
                       int* __restrict__ gcntSegT, int* __restrict__ gcntFullSegT,
                       int P, int B, int G, int ITS, int NSEG4) {
    __shared__ int sc[B_MAX * 2 * G_MAX];
    __shared__ int scFull[B_MAX * 2];
    __shared__ float s_gtb[B_MAX * GT_STRIDE];
    __shared__ float s_gvol[B_MAX * VOL_STRIDE];
    int tid = threadIdx.x;
    int q = blockIdx.x;
    int p = q * SEG_A + tid;
    int nSlots = ITS * G_MAX;
    for (int t = tid; t < nSlots; t += SEG_A) sc[t] = 0;
    if (tid < ITS) scFull[tid] = 0;
    for (int i = 0; i < B; ++i)
        for (int j = tid; j < G * 6; j += SEG_A)
            s_gtb[i * GT_STRIDE + j] = gtb[i * G * 6 + j];
    for (int i = 0; i < B; ++i)
        for (int g = tid; g < G; g += SEG_A) {
            const float* gp = gtb + ((size_t)i * G + g) * 6;
            s_gvol[i * VOL_STRIDE + g] = ((gp[3] - gp[0]) * (gp[4] - gp[1])) * (gp[5] - gp[2]);
        }
    __syncthreads();

    if (p < P) {
        int i = bidx[p];
        const float2* pp = reinterpret_cast<const float2*>(props + (size_t)p * 6);
        float2 a0 = pp[0], a1 = pp[1], a2 = pp[2];
        float b0 = a0.x, b1 = a0.y, b2 = a1.x, b3 = a1.y, b4 = a2.x, b5 = a2.y;
        float v2 = ((b3 - b0) * (b4 - b1)) * (b5 - b2);
        const float* gbase = s_gtb + i * GT_STRIDE;
        const float* vbase = s_gvol + i * VOL_STRIDE;
        float iou[G_MAX];
        float m = -1e30f;
#pragma unroll
        for (int g = 0; g < G_MAX; ++g) {
            if (g < G) {
                const float* gp = gbase + g * 6;
                float2 q0 = *reinterpret_cast<const float2*>(gp);
                float2 q1 = *reinterpret_cast<const float2*>(gp + 2);
                float2 q2 = *reinterpret_cast<const float2*>(gp + 4);
                float lo0 = fmaxf(q0.x, b0);
                float lo1 = fmaxf(q0.y, b1);
                float lo2 = fmaxf(q1.x, b2);
                float hi0 = fminf(q1.y, b3);
                float hi1 = fminf(q2.x, b4);
                float hi2 = fminf(q2.y, b5);
                float d0 = fmaxf(hi0 - lo0, 0.0f);
                float d1 = fmaxf(hi1 - lo1, 0.0f);
                float d2 = fmaxf(hi2 - lo2, 0.0f);
                float inter = (d0 * d1) * d2;
                iou[g] = inter / (((vbase[g] + v2) - inter) + EPS);
                m = fmaxf(m, iou[g]);
            } else {
                iou[g] = -2.0f;
            }
        }
        unsigned int pb = 0, nb = 0;
        if (m >= POS_THR) {
#pragma unroll
            for (int g = 0; g < G_MAX; ++g)
                if (iou[g] == m) pb |= 1u << g;
        } else if (m < NEG_THR) {  // m >= 0 always for in-image proposals
#pragma unroll
            for (int g = 0; g < G_MAX; ++g)
                if (iou[g] == m) nb |= 1u << g;
        }
        posBits[p] = pb;
        negBits[p] = nb;
        unsigned int fullMask = (G >= 32) ? 0xFFFFFFFFu : ((1u << G) - 1u);
        if (pb) {
            if (pb == fullMask) atomicAdd(&scFull[i * 2 + 0], 1);
            else {
                unsigned int t = pb;
                while (t) { int g = __ffs(t) - 1; t &= t - 1; atomicAdd(&sc[(i * 2 + 0) * G_MAX + g], 1); }
            }
        }
        if (nb) {
            if (nb == fullMask) atomicAdd(&scFull[i * 2 + 1], 1);
            else {
                unsigned int t = nb;
                while (t) { int g = __ffs(t) - 1; t &= t - 1; atomicAdd(&sc[(i * 2 + 1) * G_MAX + g], 1); }
            }
        }
    }
    __syncthreads();
    for (int t = tid; t < nSlots; t += SEG_A)
        gcntSegT[(size_t)t * NSEG4 + q] = sc[t];
    if (tid < ITS) gcntFullSegT[(size_t)tid * NSEG4 + q] = scFull[tid];
}

// Emit one valid output row. out layout: rois[B*256*6] | deltas[B*256*6] |
// labels[B*256] | tag[B*256] | ridx[B*256], all float32.
__device__ __forceinline__ void emitRow(float* __restrict__ out,
                                        const float* __restrict__ props,
                                        const float* __restrict__ gtb,
                                        const int* __restrict__ glab,
                                        int i, int s, int p, int g, bool is_pos,
                                        int B, int G) {
    float b[6], gt[6];
#pragma unroll
    for (int k = 0; k < 6; ++k) {
        b[k] = props[(size_t)p * 6 + k];
        gt[k] = gtb[((size_t)i * G + g) * 6 + k];
    }
    int row = i * TRAIN_ROIS + s;
    float* o_rois = out;
    float* o_del = out + (size_t)B * TRAIN_ROIS * 6;
    float* o_lab = o_del + (size_t)B * TRAIN_ROIS * 6;
    float* o_tag = o_lab + (size_t)B * TRAIN_ROIS;
    float* o_ridx = o_tag + (size_t)B * TRAIN_ROIS;
#pragma unroll
    for (int k = 0; k < 6; ++k) o_rois[row * 6 + k] = b[k];
    float sz0 = b[3] - b[0], sz1 = b[4] - b[1], sz2 = b[5] - b[2];
    float c0 = (b[0] + b[3]) * 0.5f, c1 = (b[1] + b[4]) * 0.5f, c2 = (b[2] + b[5]) * 0.5f;
    float gs0 = gt[3] - gt[0], gs1 = gt[4] - gt[1], gs2 = gt[5] - gt[2];
    float gc0 = (gt[0] + gt[3]) * 0.5f, gc1 = (gt[1] + gt[4]) * 0.5f, gc2 = (gt[2] + gt[5]) * 0.5f;
    o_del[row * 6 + 0] = (gc0 - c0) / sz0;
    o_del[row * 6 + 1] = (gc1 - c1) / sz1;
    o_del[row * 6 + 2] = (gc2 - c2) / sz2;
    o_del[row * 6 + 3] = logf(gs0 / sz0);
    o_del[row * 6 + 4] = logf(gs1 / sz1);
    o_del[row * 6 + 5] = logf(gs2 / sz2);
    o_lab[row] = is_pos ? (float)glab[i * G + g] : 0.0f;
    o_tag[row] = is_pos ? 1.0f : -1.0f;
    o_ridx[row] = (float)i;
}

// Solve+emit: ONE block per (image,type) — 16 blocks total, fully parallel.
// Per block: (1) wave-scan own 33 count rows (neg blocks also scan the image's
// 33 pos rows for posNum) -> per-seg exclusive prefixes in LDS; (2) thread 0:
// capped g-prefix -> off/need (+posNum/negNum); (3) 64-bit active-seg mask
// from the prefixes (only segs holding ranks < need); (4) visit ONLY active
// segments (typically 1-3): ballot-rank + direct emit, rank = LDS prefix +
// intra-seg ordered rank (no fill-state, iterations independent);
// (5) neg blocks constant-fill the invalid tail.
__launch_bounds__(1024)
__global__ void solveEmit(const float* __restrict__ props, const int* __restrict__ bidx,
                          const float* __restrict__ gtb, const int* __restrict__ glab,
                          const unsigned int* __restrict__ posBits,
                          const unsigned int* __restrict__ negBits,
                          const int* __restrict__ gcntSegT, const int* __restrict__ gcntFullSegT,
                          float* __restrict__ out,
                          int P, int B, int G, int ITS, int NSEG4) {
    int it = blockIdx.x;
    int type = it & 1;
    int i = it >> 1;
    int tid = threadIdx.x, lane = tid & 63, wid = tid >> 6;

    const int ROWSK = 2 * G_MAX + 2;       // own g|own full|pos g|pos full
    __shared__ int s_srk[ROWSK][64];
    __shared__ int s_rt[ROWSK];
    __shared__ int s_off[G_MAX], s_need[G_MAX];
    __shared__ int s_posNum, s_negNum;
    __shared__ unsigned long long s_activeSegs;
    __shared__ unsigned int s_active;
    __shared__ int s_wcnt[16][G_MAX];

    // (1) row scans: rows 0..G_MAX own g, G_MAX own full;
    //     neg blocks: G_MAX+1..2G_MAX pos g (it-1), 2G_MAX+1 pos full.
    int nRows = type ? ROWSK : (G_MAX + 1);
    for (int r = wid; r < nRows; r += 16) {
        const int* src;
        if (r < G_MAX) src = gcntSegT + (size_t)(it * G_MAX + r) * NSEG4;
        else if (r == G_MAX) src = gcntFullSegT + (size_t)it * NSEG4;
        else if (r < 2 * G_MAX + 1) src = gcntSegT + (size_t)((it - 1) * G_MAX + (r - G_MAX - 1)) * NSEG4;
        else src = gcntFullSegT + (size_t)(it - 1) * NSEG4;
        int4 v = *reinterpret_cast<const int4*>(src + lane * 4);
        int s = v.x + v.y + v.z + v.w;
        int inc = s;
        for (int d = 1; d < 64; d <<= 1) {
            int t = __shfl_up(inc, d);
            if (lane >= d) inc += t;
        }
        s_srk[r][lane] = inc - s;          // exclusive prefix at seg=lane
        if (lane == 63) s_rt[r] = inc;     // row total
    }
    __syncthreads();

    // (2) capped g-prefix (thread 0)
    if (tid == 0) {
        int posTot = 0;
        if (type) {
            int f = s_rt[2 * G_MAX + 1];
            for (int g = 0; g < G; ++g) posTot += s_rt[G_MAX + 1 + g] + f;
        } else {
            int f = s_rt[G_MAX];
            for (int g = 0; g < G; ++g) posTot += s_rt[g] + f;
        }
        int posNum = posTot < POS_QUOTA ? posTot : POS_QUOTA;
        s_posNum = posNum;
        int cap = type ? (TRAIN_ROIS - posNum) : POS_QUOTA;
        int full = s_rt[G_MAX];
        int base = 0;
        for (int g = 0; g < G_MAX; ++g) {
            int tg = (g < G) ? (s_rt[g] + full) : 0;
            s_off[g] = base;
            int nd = cap - base;
            nd = nd < 0 ? 0 : (nd > tg ? tg : nd);
            s_need[g] = nd;
            base += tg;
        }
        s_negNum = base < cap ? base : cap;   // meaningful for neg block
    }
    __syncthreads();

    // (3) active-seg mask (wave 0; lane = seg)
    if (tid < 64) {
        int fullv = s_srk[G_MAX][tid];
        bool act = false;
        for (int g = 0; g < G; ++g)
            act |= (s_srk[g][tid] + fullv) < s_need[g];
        unsigned long long bal = __ballot(act);
        if (tid == 0) s_activeSegs = bal;
    }
    __syncthreads();

    // (5) tail-fill (neg block; disjoint rows, no ordering hazard)
    if (type) {
        int slotEnd = s_posNum + s_negNum;
        float* o_rois = out;
        float* o_del = out + (size_t)B * TRAIN_ROIS * 6;
        float* o_lab = o_del + (size_t)B * TRAIN_ROIS * 6;
        float* o_tag = o_lab + (size_t)B * TRAIN_ROIS;
        float* o_ridx = o_tag + (size_t)B * TRAIN_ROIS;
        for (int s = slotEnd + tid; s < TRAIN_ROIS; s += 1024) {
            int row = i * TRAIN_ROIS + s;
#pragma unroll
            for (int k = 0; k < 6; ++k) {
                o_rois[row * 6 + k] = 0.0f;
                o_del[row * 6 + k] = 0.0f;
            }
            o_lab[row] = 0.0f;
            o_tag[row] = 0.0f;
            o_ridx[row] = -1.0f;
        }
    }

    // (4) visit active segments only
    unsigned long long segs = s_activeSegs;
    int slotBase = type ? s_posNum : 0;
    unsigned long long laneLt = (1ull << lane) - 1ull;
    const unsigned int* bits = type ? negBits : posBits;

    while (segs) {
        int seg = __ffsll((long long)segs) - 1;
        segs &= segs - 1;

        // per-seg active-g mask
        if (tid < G_MAX) {
            bool a = (s_srk[tid][seg] + s_srk[G_MAX][seg]) < s_need[tid];
            unsigned long long bal = __ballot(a);
            if (tid == 0) s_active = (unsigned int)bal;
        }
        __syncthreads();
        unsigned int active = s_active;

        int p = seg * SEG + tid;
        unsigned int mask = 0;
        if (p < P && bidx[p] == i)
            mask = bits[p] & active;

        // per-wave counts for active g's
        unsigned int am = active;
        while (am) {
            int g = __ffs(am) - 1; am &= am - 1;
            unsigned long long bal = __ballot((mask >> g) & 1u);
            if (lane == 0) s_wcnt[wid][g] = __popcll(bal);
        }
        __syncthreads();
        // exclusive prefix across the 16 waves (thread g handles bucket g)
        if (tid < G_MAX && ((active >> tid) & 1u)) {
            int run = 0;
#pragma unroll
            for (int w = 0; w < 16; ++w) {
                int c = s_wcnt[w][tid];
                s_wcnt[w][tid] = run;
                run += c;
            }
        }
        __syncthreads();
        // placement + direct output emit
        am = active;
        while (am) {
            int g = __ffs(am) - 1; am &= am - 1;
            bool bit = (mask >> g) & 1u;
            unsigned long long bal = __ballot(bit);
            if (bit) {
                int r = s_srk[g][seg] + s_srk[G_MAX][seg] + s_wcnt[wid][g] + __popcll(bal & laneLt);
                if (r < s_need[g])
                    emitRow(out, props, gtb, glab, i, slotBase + s_off[g] + r, p, g,
                            type == 0, B, G);
            }
        }
        __syncthreads();   // protect s_active/s_wcnt before next iteration
    }
}

extern "C" void kernel_launch(void* const* d_in, const int* in_sizes, int n_in,
                              void* d_out, int out_size, void* d_ws, size_t ws_size,
                              hipStream_t stream) {
    const float* props = (const float*)d_in[0];
    const int* bidx = (const int*)d_in[1];
    const float* gtb = (const float*)d_in[2];
    const int* glab = (const int*)d_in[3];
    int P = in_sizes[1];                       // 65536
    int B = out_size / (TRAIN_ROIS * 15);      // 6+6+1+1+1 per slot -> 8
    int G = in_sizes[3] / B;                   // 32
    int ITS = B * 2;                           // 16
    int NSEG4 = (P + SEG_A - 1) / SEG_A;       // 256 quarters
    int nSlots = ITS * G_MAX;                  // 512

    unsigned int* posBits = (unsigned int*)d_ws;            // [P]
    unsigned int* negBits = posBits + (size_t)P;            // [P]
    int* gcntSegT = (int*)(negBits + (size_t)P);            // [nSlots][NSEG4]
    int* gcntFullSegT = gcntSegT + (size_t)nSlots * NSEG4;  // [ITS][NSEG4]

    phaseA<<<NSEG4, SEG_A, 0, stream>>>(props, bidx, gtb, posBits, negBits,
                                        gcntSegT, gcntFullSegT, P, B, G, ITS, NSEG4);
    solveEmit<<<ITS, SEG, 0, stream>>>(props, bidx, gtb, glab,
                                       posBits, negBits,
                                       gcntSegT, gcntFullSegT,
                                       (float*)d_out, P, B, G, ITS, NSEG4);
}

// Round 16
// 35.288 us; speedup vs baseline: 2.6151x; 2.6151x over previous
//
#include <hip/hip_runtime.h>

#define TRAIN_ROIS 256
#define POS_QUOTA 25          // int(0.1 * 256)
#define POS_THR 0.5f
#define NEG_THR 0.02f
#define EPS 1e-8f
#define G_MAX 32
#define B_MAX 16
#define SEG 1024              // placeEmit segment (= its block size)
#define SEG_A 256             // phaseA quarter-segment (= its block size)
#define GT_STRIDE 194         // even (float2-aligned); i*194%32=2i -> disjoint bank pairs
#define VOL_STRIDE 33         // (i*33+g)%32=(i+g)%32 -> bank-spread volumes

// Phase A: one thread per proposal, block = 256-p quarter-segment (256 blocks
// -> all CUs). gt boxes staged bank-conflict-free in LDS; per-gt volumes
// precomputed. IoU keeps the reference's exact left-assoc arithmetic.
// Per-quarter counts stored transposed: gcntSegT[slot][quarter], slot=it*32+g;
// full-mask (all-G tie, the common iou==0 neg case) counted separately.
__launch_bounds__(SEG_A)
__global__ void phaseA(const float* __restrict__ props, const int* __restrict__ bidx,
                       const float* __restrict__ gtb,
                       unsigned int* __restrict__ posBits, unsigned int* __restrict__ negBits,
                       int* __restrict__ gcntSegT, int* __restrict__ gcntFullSegT,
                       int P, int B, int G, int ITS, int NSEG4) {
    __shared__ int sc[B_MAX * 2 * G_MAX];
    __shared__ int scFull[B_MAX * 2];
    __shared__ float s_gtb[B_MAX * GT_STRIDE];
    __shared__ float s_gvol[B_MAX * VOL_STRIDE];
    int tid = threadIdx.x;
    int q = blockIdx.x;
    int p = q * SEG_A + tid;
    int nSlots = ITS * G_MAX;
    for (int t = tid; t < nSlots; t += SEG_A) sc[t] = 0;
    if (tid < ITS) scFull[tid] = 0;
    for (int i = 0; i < B; ++i)
        for (int j = tid; j < G * 6; j += SEG_A)
            s_gtb[i * GT_STRIDE + j] = gtb[i * G * 6 + j];
    for (int i = 0; i < B; ++i)
        for (int g = tid; g < G; g += SEG_A) {
            const float* gp = gtb + ((size_t)i * G + g) * 6;
            s_gvol[i * VOL_STRIDE + g] = ((gp[3] - gp[0]) * (gp[4] - gp[1])) * (gp[5] - gp[2]);
        }
    __syncthreads();

    if (p < P) {
        int i = bidx[p];
        const float2* pp = reinterpret_cast<const float2*>(props + (size_t)p * 6);
        float2 a0 = pp[0], a1 = pp[1], a2 = pp[2];
        float b0 = a0.x, b1 = a0.y, b2 = a1.x, b3 = a1.y, b4 = a2.x, b5 = a2.y;
        float v2 = ((b3 - b0) * (b4 - b1)) * (b5 - b2);
        const float* gbase = s_gtb + i * GT_STRIDE;
        const float* vbase = s_gvol + i * VOL_STRIDE;
        float iou[G_MAX];
        float m = -1e30f;
#pragma unroll
        for (int g = 0; g < G_MAX; ++g) {
            if (g < G) {
                const float* gp = gbase + g * 6;
                float2 q0 = *reinterpret_cast<const float2*>(gp);
                float2 q1 = *reinterpret_cast<const float2*>(gp + 2);
                float2 q2 = *reinterpret_cast<const float2*>(gp + 4);
                float lo0 = fmaxf(q0.x, b0);
                float lo1 = fmaxf(q0.y, b1);
                float lo2 = fmaxf(q1.x, b2);
                float hi0 = fminf(q1.y, b3);
                float hi1 = fminf(q2.x, b4);
                float hi2 = fminf(q2.y, b5);
                float d0 = fmaxf(hi0 - lo0, 0.0f);
                float d1 = fmaxf(hi1 - lo1, 0.0f);
                float d2 = fmaxf(hi2 - lo2, 0.0f);
                float inter = (d0 * d1) * d2;
                iou[g] = inter / (((vbase[g] + v2) - inter) + EPS);
                m = fmaxf(m, iou[g]);
            } else {
                iou[g] = -2.0f;
            }
        }
        unsigned int pb = 0, nb = 0;
        if (m >= POS_THR) {
#pragma unroll
            for (int g = 0; g < G_MAX; ++g)
                if (iou[g] == m) pb |= 1u << g;
        } else if (m < NEG_THR) {  // m >= 0 always for in-image proposals
#pragma unroll
            for (int g = 0; g < G_MAX; ++g)
                if (iou[g] == m) nb |= 1u << g;
        }
        posBits[p] = pb;
        negBits[p] = nb;
        unsigned int fullMask = (G >= 32) ? 0xFFFFFFFFu : ((1u << G) - 1u);
        if (pb) {
            if (pb == fullMask) atomicAdd(&scFull[i * 2 + 0], 1);
            else {
                unsigned int t = pb;
                while (t) { int g = __ffs(t) - 1; t &= t - 1; atomicAdd(&sc[(i * 2 + 0) * G_MAX + g], 1); }
            }
        }
        if (nb) {
            if (nb == fullMask) atomicAdd(&scFull[i * 2 + 1], 1);
            else {
                unsigned int t = nb;
                while (t) { int g = __ffs(t) - 1; t &= t - 1; atomicAdd(&sc[(i * 2 + 1) * G_MAX + g], 1); }
            }
        }
    }
    __syncthreads();
    for (int t = tid; t < nSlots; t += SEG_A)
        gcntSegT[(size_t)t * NSEG4 + q] = sc[t];
    if (tid < ITS) gcntFullSegT[(size_t)tid * NSEG4 + q] = scFull[tid];
}

// Scan: one block per image (8 waves). Each wave handles one count row of
// NSEG4=256 ints (4/lane int4 + 6-step shfl_up wave scan) -> per-SEG exclusive
// prefixes (lane s = quarters 4s..4s+3) + row total. Thread 0 then does the
// capped 32-g prefix for pos (cap 25) and neg (cap 256-posNum) and writes
// off/need/posNum/slotEnd. Kills ALL redundant row-summing downstream.
__launch_bounds__(512)
__global__ void scanKernel(const int* __restrict__ gcntSegT, const int* __restrict__ gcntFullSegT,
                           int* __restrict__ srkSeg, int* __restrict__ fullSeg,
                           int* __restrict__ offA, int* __restrict__ needA,
                           int* __restrict__ posNumArr, int* __restrict__ slotEndArr,
                           int B, int G, int NSEG4, int NSEGP) {
    int i = blockIdx.x;
    int tid = threadIdx.x, lane = tid & 63, w = tid >> 6;
    __shared__ int s_rt[2 * G_MAX + 2];   // rows: pos g / posFull / neg g / negFull
    const int ROWS = 2 * G_MAX + 2;
    for (int r = w; r < ROWS; r += 8) {
        const int* src;
        int* dst;
        if (r < G_MAX) {
            int slot = (2 * i) * G_MAX + r;
            src = gcntSegT + (size_t)slot * NSEG4;
            dst = srkSeg + (size_t)slot * NSEGP;
        } else if (r == G_MAX) {
            src = gcntFullSegT + (size_t)(2 * i) * NSEG4;
            dst = fullSeg + (size_t)(2 * i) * NSEGP;
        } else if (r < 2 * G_MAX + 1) {
            int slot = (2 * i + 1) * G_MAX + (r - G_MAX - 1);
            src = gcntSegT + (size_t)slot * NSEG4;
            dst = srkSeg + (size_t)slot * NSEGP;
        } else {
            src = gcntFullSegT + (size_t)(2 * i + 1) * NSEG4;
            dst = fullSeg + (size_t)(2 * i + 1) * NSEGP;
        }
        int4 v = *reinterpret_cast<const int4*>(src + lane * 4);
        int s = v.x + v.y + v.z + v.w;
        int inc = s;
        for (int d = 1; d < 64; d <<= 1) {
            int t = __shfl_up(inc, d);
            if (lane >= d) inc += t;
        }
        dst[lane] = inc - s;              // exclusive prefix at quarter 4*lane
        if (lane == 63) s_rt[r] = inc;    // row total
    }
    __syncthreads();
    if (tid == 0) {
        int fullTot = s_rt[G_MAX];
        int base = 0;
        for (int g = 0; g < G; ++g) {
            int tg = s_rt[g] + fullTot;
            offA[(2 * i) * G_MAX + g] = base;
            int nd = POS_QUOTA - base;
            nd = nd < 0 ? 0 : (nd > tg ? tg : nd);
            needA[(2 * i) * G_MAX + g] = nd;
            base += tg;
        }
        int posNum = base < POS_QUOTA ? base : POS_QUOTA;
        posNumArr[i] = posNum;
        int fullTotN = s_rt[2 * G_MAX + 1];
        int capN = TRAIN_ROIS - posNum;
        int baseN = 0;
        for (int g = 0; g < G; ++g) {
            int tg = s_rt[G_MAX + 1 + g] + fullTotN;
            offA[(2 * i + 1) * G_MAX + g] = baseN;
            int nd = capN - baseN;
            nd = nd < 0 ? 0 : (nd > tg ? tg : nd);
            needA[(2 * i + 1) * G_MAX + g] = nd;
            baseN += tg;
        }
        int negNum = baseN < capN ? baseN : capN;
        slotEndArr[i] = posNum + negNum;
    }
}

// Emit one valid output row. out layout: rois[B*256*6] | deltas[B*256*6] |
// labels[B*256] | tag[B*256] | ridx[B*256], all float32.
__device__ __forceinline__ void emitRow(float* __restrict__ out,
                                        const float* __restrict__ props,
                                        const float* __restrict__ gtb,
                                        const int* __restrict__ glab,
                                        int i, int s, int p, int g, bool is_pos,
                                        int B, int G) {
    float b[6], gt[6];
#pragma unroll
    for (int k = 0; k < 6; ++k) {
        b[k] = props[(size_t)p * 6 + k];
        gt[k] = gtb[((size_t)i * G + g) * 6 + k];
    }
    int row = i * TRAIN_ROIS + s;
    float* o_rois = out;
    float* o_del = out + (size_t)B * TRAIN_ROIS * 6;
    float* o_lab = o_del + (size_t)B * TRAIN_ROIS * 6;
    float* o_tag = o_lab + (size_t)B * TRAIN_ROIS;
    float* o_ridx = o_tag + (size_t)B * TRAIN_ROIS;
#pragma unroll
    for (int k = 0; k < 6; ++k) o_rois[row * 6 + k] = b[k];
    float sz0 = b[3] - b[0], sz1 = b[4] - b[1], sz2 = b[5] - b[2];
    float c0 = (b[0] + b[3]) * 0.5f, c1 = (b[1] + b[4]) * 0.5f, c2 = (b[2] + b[5]) * 0.5f;
    float gs0 = gt[3] - gt[0], gs1 = gt[4] - gt[1], gs2 = gt[5] - gt[2];
    float gc0 = (gt[0] + gt[3]) * 0.5f, gc1 = (gt[1] + gt[4]) * 0.5f, gc2 = (gt[2] + gt[5]) * 0.5f;
    o_del[row * 6 + 0] = (gc0 - c0) / sz0;
    o_del[row * 6 + 1] = (gc1 - c1) / sz1;
    o_del[row * 6 + 2] = (gc2 - c2) / sz2;
    o_del[row * 6 + 3] = logf(gs0 / sz0);
    o_del[row * 6 + 4] = logf(gs1 / sz1);
    o_del[row * 6 + 5] = logf(gs2 / sz2);
    o_lab[row] = is_pos ? (float)glab[i * G + g] : 0.0f;
    o_tag[row] = is_pos ? 1.0f : -1.0f;
    o_ridx[row] = (float)i;
}

// Place+emit: one block per (segment, it). Reads ONLY precomputed scalars
// (srk at its seg boundary, off, need, posNum, slotEnd) — no row sums. Single
// ballot pass places this segment's matches in first-k flat order and writes
// the 15 output floats directly. (seg==0, neg) block fills the invalid tail.
__launch_bounds__(1024)
__global__ void placeEmit(const float* __restrict__ props, const int* __restrict__ bidx,
                          const float* __restrict__ gtb, const int* __restrict__ glab,
                          const unsigned int* __restrict__ posBits,
                          const unsigned int* __restrict__ negBits,
                          const int* __restrict__ srkSeg, const int* __restrict__ fullSeg,
                          const int* __restrict__ offA, const int* __restrict__ needA,
                          const int* __restrict__ posNumArr, const int* __restrict__ slotEndArr,
                          float* __restrict__ out,
                          int P, int B, int G, int ITS, int NSEGP) {
    int blk = blockIdx.x;
    int seg = blk / ITS;
    int it = blk - seg * ITS;
    int type = it & 1;
    int i = it >> 1;

    __shared__ int s_srk[G_MAX], s_off[G_MAX], s_need[G_MAX];
    __shared__ int s_posNum;
    __shared__ unsigned int s_active;
    __shared__ int s_wcnt[16][G_MAX];

    int tid = threadIdx.x, lane = tid & 63, wid = tid >> 6;

    if (tid < G_MAX) {
        int srk = srkSeg[(size_t)(it * G_MAX + tid) * NSEGP + seg]
                + fullSeg[(size_t)it * NSEGP + seg];
        int nd = needA[it * G_MAX + tid];
        s_srk[tid] = srk;
        s_off[tid] = offA[it * G_MAX + tid];
        s_need[tid] = nd;
        unsigned long long bal = __ballot(srk < nd);
        if (tid == 0) {
            s_active = (unsigned int)bal;
            s_posNum = posNumArr[i];
        }
    }
    __syncthreads();

    // constant-fill the invalid tail (one designated block per image)
    if (type && seg == 0) {
        int slotEnd = slotEndArr[i];
        float* o_rois = out;
        float* o_del = out + (size_t)B * TRAIN_ROIS * 6;
        float* o_lab = o_del + (size_t)B * TRAIN_ROIS * 6;
        float* o_tag = o_lab + (size_t)B * TRAIN_ROIS;
        float* o_ridx = o_tag + (size_t)B * TRAIN_ROIS;
        for (int s = slotEnd + tid; s < TRAIN_ROIS; s += blockDim.x) {
            int row = i * TRAIN_ROIS + s;
#pragma unroll
            for (int k = 0; k < 6; ++k) {
                o_rois[row * 6 + k] = 0.0f;
                o_del[row * 6 + k] = 0.0f;
            }
            o_lab[row] = 0.0f;
            o_tag[row] = 0.0f;
            o_ridx[row] = -1.0f;
        }
    }

    unsigned int active = s_active;
    if (!active) return;
    int slotBase = type ? s_posNum : 0;

    int p = seg * SEG + tid;
    unsigned int mask = 0;
    if (p < P && bidx[p] == i)
        mask = (type ? negBits : posBits)[p] & active;

    // per-wave counts for active g's
    unsigned int am = active;
    while (am) {
        int g = __ffs(am) - 1; am &= am - 1;
        unsigned long long bal = __ballot((mask >> g) & 1u);
        if (lane == 0) s_wcnt[wid][g] = __popcll(bal);
    }
    __syncthreads();
    // exclusive prefix across the 16 waves (thread g handles bucket g)
    if (tid < G_MAX && ((active >> tid) & 1u)) {
        int run = 0;
#pragma unroll
        for (int w = 0; w < 16; ++w) {
            int c = s_wcnt[w][tid];
            s_wcnt[w][tid] = run;
            run += c;
        }
    }
    __syncthreads();
    // placement + direct output emit
    unsigned long long laneLt = (1ull << lane) - 1ull;
    am = active;
    while (am) {
        int g = __ffs(am) - 1; am &= am - 1;
        bool bit = (mask >> g) & 1u;
        unsigned long long bal = __ballot(bit);
        if (bit) {
            int r = s_srk[g] + s_wcnt[wid][g] + __popcll(bal & laneLt);
            if (r < s_need[g])
                emitRow(out, props, gtb, glab, i, slotBase + s_off[g] + r, p, g,
                        type == 0, B, G);
        }
    }
}

extern "C" void kernel_launch(void* const* d_in, const int* in_sizes, int n_in,
                              void* d_out, int out_size, void* d_ws, size_t ws_size,
                              hipStream_t stream) {
    const float* props = (const float*)d_in[0];
    const int* bidx = (const int*)d_in[1];
    const float* gtb = (const float*)d_in[2];
    const int* glab = (const int*)d_in[3];
    int P = in_sizes[1];                       // 65536
    int B = out_size / (TRAIN_ROIS * 15);      // 6+6+1+1+1 per slot -> 8
    int G = in_sizes[3] / B;                   // 32
    int ITS = B * 2;                           // 16
    int NSEG = (P + SEG - 1) / SEG;            // 64   (place segments)
    int NSEG4 = (P + SEG_A - 1) / SEG_A;       // 256  (phaseA quarters; =4*NSEG)
    int nSlots = ITS * G_MAX;                  // 512

    unsigned int* posBits = (unsigned int*)d_ws;            // [P]
    unsigned int* negBits = posBits + (size_t)P;            // [P]
    int* gcntSegT = (int*)(negBits + (size_t)P);            // [nSlots][NSEG4]
    int* gcntFullSegT = gcntSegT + (size_t)nSlots * NSEG4;  // [ITS][NSEG4]
    int* srkSeg = gcntFullSegT + (size_t)ITS * NSEG4;       // [nSlots][NSEG]
    int* fullSeg = srkSeg + (size_t)nSlots * NSEG;          // [ITS][NSEG]
    int* offA = fullSeg + (size_t)ITS * NSEG;               // [ITS][32]
    int* needA = offA + nSlots;                             // [ITS][32]
    int* posNumArr = needA + nSlots;                        // [B]
    int* slotEndArr = posNumArr + B;                        // [B]

    phaseA<<<NSEG4, SEG_A, 0, stream>>>(props, bidx, gtb, posBits, negBits,
                                        gcntSegT, gcntFullSegT, P, B, G, ITS, NSEG4);
    scanKernel<<<B, 512, 0, stream>>>(gcntSegT, gcntFullSegT, srkSeg, fullSeg,
                                      offA, needA, posNumArr, slotEndArr,
                                      B, G, NSEG4, NSEG);
    placeEmit<<<NSEG * ITS, SEG, 0, stream>>>(props, bidx, gtb, glab,
                                              posBits, negBits,
                                              srkSeg, fullSeg, offA, needA,
                                              posNumArr, slotEndArr,
                                              (float*)d_out, P, B, G, ITS, NSEG);
}